// Round 1
// baseline (942.938 us; speedup 1.0000x reference)
//
#include <hip/hip_runtime.h>

#define HID      256
#define DDYN     5
#define NS       27
#define TS       365
#define BS       4          // batch rows per block
#define COLSW    192        // gate columns per wave
#define NTILE    12         // 16-col tiles per wave
#define STRIDE_A 296        // A-buffer row stride in bf16 elems (256 h + 32 xpad + 8 pad)
#define G3       768        // 3 gates * 256

typedef short short8 __attribute__((ext_vector_type(8)));
typedef float f32x4  __attribute__((ext_vector_type(4)));

__device__ __forceinline__ unsigned short f2bf(float f) {
    union { float f; unsigned u; } v; v.f = f;
    unsigned r = v.u + 0x7FFFu + ((v.u >> 16) & 1u);   // RNE
    return (unsigned short)(r >> 16);
}
__device__ __forceinline__ float fsig(float x) {
    // 1/(1+2^(-x*log2e))
    float e = __builtin_amdgcn_exp2f(-1.4426950408889634f * x);
    return __builtin_amdgcn_rcpf(1.0f + e);
}
__device__ __forceinline__ float ftanh(float x) {
    // 1 - 2/(1+2^(2x*log2e))
    float e = __builtin_amdgcn_exp2f(2.8853900817779268f * x);
    return 1.0f - 2.0f * __builtin_amdgcn_rcpf(1.0f + e);
}

__global__ __launch_bounds__(256, 1)
void ealstm_kernel(const float* __restrict__ x_dyn,  const float* __restrict__ x_stat,
                   const float* __restrict__ W_i,    const float* __restrict__ b_i,
                   const float* __restrict__ W_f,    const float* __restrict__ b_f,
                   const float* __restrict__ W_g,    const float* __restrict__ b_g,
                   const float* __restrict__ W_o,    const float* __restrict__ b_o,
                   const float* __restrict__ W_head, const float* __restrict__ b_head,
                   float* __restrict__ out)
{
    // LDS: 9472 + 12288 + 12288 + 14600 + 432 = ~49 KB
    __shared__ __align__(16) unsigned short Abuf[16 * STRIDE_A]; // A tile: 16 rows x 288 K (bf16)
    __shared__ __align__(16) float          pre[G3 * 4];         // preacts [col][4 rows]
    __shared__ __align__(16) unsigned short WxL[G3 * 8];         // B rows 256..263: Wx[0..4],bias,0,0
    __shared__ __align__(16) unsigned short xc[TS * 20];         // x cache [t][b][d] bf16
    __shared__ __align__(16) float          xst[BS * NS];

    const int tid  = threadIdx.x;
    const int bid  = blockIdx.x;
    const int b0   = bid * BS;
    const int lane = tid & 63;
    const int wv   = tid >> 6;      // wave 0..3
    const int q    = lane >> 4;     // quad 0..3
    const int n    = lane & 15;

    // ---- init LDS ----
    for (int i = tid; i < 16 * STRIDE_A / 2; i += 256)
        ((unsigned int*)Abuf)[i] = 0u;                 // zero A (h0=0, pad cols=0)
    for (int i = tid; i < BS * NS; i += 256)
        xst[i] = x_stat[(b0 + i / NS) * NS + (i % NS)];
    for (int i = tid; i < TS * BS * DDYN; i += 256) {
        int b  = i / (TS * DDYN);
        int rr = i - b * (TS * DDYN);
        int t  = rr / DDYN;
        int d  = rr - t * DDYN;
        xc[t * 20 + b * DDYN + d] =
            f2bf(x_dyn[(size_t)(b0 + b) * (TS * DDYN) + t * DDYN + d]);
    }
    for (int col = tid; col < G3; col += 256) {
        int gate = col >> 8, hc = col & 255;
        const float* Wg = gate == 0 ? W_f : (gate == 1 ? W_g : W_o);
        const float* bg = gate == 0 ? b_f : (gate == 1 ? b_g : b_o);
        #pragma unroll
        for (int d = 0; d < DDYN; d++) WxL[col * 8 + d] = f2bf(Wg[hc * (DDYN + HID) + d]);
        WxL[col * 8 + 5] = f2bf(bg[hc]);
        WxL[col * 8 + 6] = 0; WxL[col * 8 + 7] = 0;
    }
    __syncthreads();
    if (tid < BS) Abuf[tid * STRIDE_A + 261] = 0x3F80;  // bias column = 1.0
    if (tid < BS * DDYN) {                               // stage x(t=0)
        int r = tid / DDYN, d = tid - r * DDYN;
        Abuf[r * STRIDE_A + 256 + d] = xc[r * DDYN + d];
    }

    // ---- persistent B fragments (h-part weights) in VGPRs: 12 tiles x 8 K-chunks ----
    short8 Bf[NTILE][8];
    #pragma unroll
    for (int j = 0; j < NTILE; j++) {
        int col = wv * COLSW + j * 16 + n;
        int gate = col >> 8, hc = col & 255;
        const float* Wg = gate == 0 ? W_f : (gate == 1 ? W_g : W_o);
        const float* wrow = Wg + hc * (DDYN + HID) + DDYN;   // skip x-part
        #pragma unroll
        for (int c = 0; c < 8; c++) {
            int k0 = c * 32 + q * 8;
            short8 fr;
            #pragma unroll
            for (int e = 0; e < 8; e++) fr[e] = (short)f2bf(wrow[k0 + e]);
            Bf[j][c] = fr;
        }
    }

    // ---- i_gate (once), head weight ----
    float ig[BS], cst[BS], hfin[BS];
    {
        float a0 = b_i[tid], a1 = a0, a2 = a0, a3 = a0;
        for (int s = 0; s < NS; s++) {
            float w = W_i[tid * NS + s];
            a0 += xst[0 * NS + s] * w;  a1 += xst[1 * NS + s] * w;
            a2 += xst[2 * NS + s] * w;  a3 += xst[3 * NS + s] * w;
        }
        ig[0] = fsig(a0); ig[1] = fsig(a1); ig[2] = fsig(a2); ig[3] = fsig(a3);
    }
    cst[0] = cst[1] = cst[2] = cst[3] = 0.0f;
    float whead = W_head[tid];
    __syncthreads();

    const int aoff = n * STRIDE_A;

    // ---- time loop ----
    for (int t = 0; t < TS; t++) {
        // Phase A: gates = [h | x | 1 | 0] @ [Wh | Wx | b | 0]^T  via MFMA
        f32x4 acc[NTILE];
        #pragma unroll
        for (int j = 0; j < NTILE; j++) acc[j] = (f32x4){0.f, 0.f, 0.f, 0.f};
        #pragma unroll
        for (int c = 0; c < 8; c++) {
            short8 a = *(const short8*)&Abuf[aoff + c * 32 + q * 8];
            #pragma unroll
            for (int j = 0; j < NTILE; j++)
                acc[j] = __builtin_amdgcn_mfma_f32_16x16x32_bf16(a, Bf[j][c], acc[j], 0, 0, 0);
        }
        {   // K-chunk 8: x-part + bias (A cols 262..287 are zero)
            short8 a8 = *(const short8*)&Abuf[aoff + 256 + q * 8];
            #pragma unroll
            for (int j = 0; j < NTILE; j++) {
                short8 b8 = {};
                if (q == 0) b8 = *(const short8*)&WxL[(wv * COLSW + j * 16 + n) * 8];
                acc[j] = __builtin_amdgcn_mfma_f32_16x16x32_bf16(a8, b8, acc[j], 0, 0, 0);
            }
        }
        if (q == 0) {   // lanes 0..15 hold rows 0..3 (valid batch rows) of their col
            #pragma unroll
            for (int j = 0; j < NTILE; j++)
                *(f32x4*)&pre[(wv * COLSW + j * 16 + n) * 4] = acc[j];
        }
        __syncthreads();

        // Phase B: elementwise LSTM cell; thread tid owns hidden unit `tid`, rows 0..3
        f32x4 pf = *(const f32x4*)&pre[tid * 4];
        f32x4 pg = *(const f32x4*)&pre[(256 + tid) * 4];
        f32x4 po = *(const f32x4*)&pre[(512 + tid) * 4];
        #pragma unroll
        for (int r = 0; r < BS; r++) {
            float f  = fsig(pf[r]);
            float g  = ftanh(pg[r]);
            float o  = fsig(po[r]);
            float cr = f * cst[r] + ig[r] * g;
            cst[r]   = cr;
            float h  = o * ftanh(cr);
            Abuf[r * STRIDE_A + tid] = f2bf(h);
            if (t == TS - 1) hfin[r] = h;
        }
        if (t + 1 < TS && tid < BS * DDYN) {   // stage x(t+1)
            int r = tid / DDYN, d = tid - r * DDYN;
            Abuf[r * STRIDE_A + 256 + d] = xc[(t + 1) * 20 + r * DDYN + d];
        }
        __syncthreads();
    }

    // ---- head: out[b] = h . W_head + b_head ----
    {
        f32x4 p;
        #pragma unroll
        for (int r = 0; r < BS; r++) p[r] = hfin[r] * whead;
        *(f32x4*)&pre[tid * 4] = p;
        __syncthreads();
        if (tid < 64) {
            f32x4 s = *(const f32x4*)&pre[tid * 4];
            #pragma unroll
            for (int k = 1; k < 4; k++) {
                f32x4 v = *(const f32x4*)&pre[(tid + k * 64) * 4];
                #pragma unroll
                for (int r = 0; r < BS; r++) s[r] += v[r];
            }
            #pragma unroll
            for (int off = 32; off > 0; off >>= 1)
                #pragma unroll
                for (int r = 0; r < BS; r++) s[r] += __shfl_down(s[r], off, 64);
            if (tid == 0) {
                float bh = b_head[0];
                #pragma unroll
                for (int r = 0; r < BS; r++) out[b0 + r] = s[r] + bh;
            }
        }
    }
}

extern "C" void kernel_launch(void* const* d_in, const int* in_sizes, int n_in,
                              void* d_out, int out_size, void* d_ws, size_t ws_size,
                              hipStream_t stream) {
    ealstm_kernel<<<256, 256, 0, stream>>>(
        (const float*)d_in[0],  (const float*)d_in[1],  (const float*)d_in[2],
        (const float*)d_in[3],  (const float*)d_in[4],  (const float*)d_in[5],
        (const float*)d_in[6],  (const float*)d_in[7],  (const float*)d_in[8],
        (const float*)d_in[9],  (const float*)d_in[10], (const float*)d_in[11],
        (float*)d_out);
}

// Round 2
// 707.900 us; speedup vs baseline: 1.3320x; 1.3320x over previous
//
#include <hip/hip_runtime.h>

#define HID      256
#define DDYN     5
#define NS       27
#define TS       365
#define BS       4          // batch rows per block
#define NW       8          // waves per block
#define UPW      32         // hidden units owned per wave
#define NTILE    6          // 16-col MFMA tiles per wave (32 units x 3 gates / 16)
#define STRIDE_A 296        // A-buffer row stride in bf16 elems (256 h + 32 xpad + 8 pad)
#define G3       768        // 3 gates * 256

typedef short short8 __attribute__((ext_vector_type(8)));
typedef float f32x4  __attribute__((ext_vector_type(4)));
typedef float f32x2  __attribute__((ext_vector_type(2)));

__device__ __forceinline__ unsigned short f2bf(float f) {
    union { float f; unsigned u; } v; v.f = f;
    unsigned r = v.u + 0x7FFFu + ((v.u >> 16) & 1u);   // RNE
    return (unsigned short)(r >> 16);
}
__device__ __forceinline__ float fsig(float x) {
    float e = __builtin_amdgcn_exp2f(-1.4426950408889634f * x);
    return __builtin_amdgcn_rcpf(1.0f + e);
}
__device__ __forceinline__ float ftanh(float x) {
    float e = __builtin_amdgcn_exp2f(2.8853900817779268f * x);
    return 1.0f - 2.0f * __builtin_amdgcn_rcpf(1.0f + e);
}

__global__ __launch_bounds__(512, 2)
void ealstm_kernel(const float* __restrict__ x_dyn,  const float* __restrict__ x_stat,
                   const float* __restrict__ W_i,    const float* __restrict__ b_i,
                   const float* __restrict__ W_f,    const float* __restrict__ b_f,
                   const float* __restrict__ W_g,    const float* __restrict__ b_g,
                   const float* __restrict__ W_o,    const float* __restrict__ b_o,
                   const float* __restrict__ W_head, const float* __restrict__ b_head,
                   float* __restrict__ out)
{
    // LDS: 18944 + 12288 + 12288 + 14600 + 432 = ~58.6 KB (1 block/CU)
    __shared__ __align__(16) unsigned short Abuf[2][16 * STRIDE_A]; // double-buffered A tile
    __shared__ __align__(16) float          pre[G3 * 4];            // preacts [col][4 rows]
    __shared__ __align__(16) unsigned short WxL[G3 * 8];            // B rows 256..263: Wx[0..4],bias,0,0
    __shared__ __align__(16) unsigned short xc[TS * 20];            // x cache [t][b][d] bf16
    __shared__ __align__(16) float          xst[BS * NS];

    const int tid  = threadIdx.x;
    const int bid  = blockIdx.x;
    const int b0   = bid * BS;
    const int lane = tid & 63;
    const int wv   = tid >> 6;        // wave 0..7
    const int q    = lane >> 4;       // quad 0..3 (MFMA K-group)
    const int n    = lane & 15;       // MFMA col-in-tile / batch row for A
    const int ul   = lane & 31;       // unit-local 0..31 (phase B)
    const int r0   = (lane >> 5) * 2; // rows {0,1} or {2,3} (phase B)
    const int u    = wv * UPW + ul;   // owned hidden unit

    // ---- init LDS ----
    for (int i = tid; i < 2 * 16 * STRIDE_A / 2; i += 512)
        ((unsigned int*)Abuf)[i] = 0u;                 // zero both A buffers
    for (int i = tid; i < BS * NS; i += 512)
        xst[i] = x_stat[(b0 + i / NS) * NS + (i % NS)];
    for (int i = tid; i < TS * BS * DDYN; i += 512) {
        int b  = i / (TS * DDYN);
        int rr = i - b * (TS * DDYN);
        int t  = rr / DDYN;
        int d  = rr - t * DDYN;
        xc[t * 20 + b * DDYN + d] =
            f2bf(x_dyn[(size_t)(b0 + b) * (TS * DDYN) + t * DDYN + d]);
    }
    for (int col = tid; col < G3; col += 512) {
        int gate = col >> 8, hc = col & 255;
        const float* Wg = gate == 0 ? W_f : (gate == 1 ? W_g : W_o);
        const float* bg = gate == 0 ? b_f : (gate == 1 ? b_g : b_o);
        #pragma unroll
        for (int d = 0; d < DDYN; d++) WxL[col * 8 + d] = f2bf(Wg[hc * (DDYN + HID) + d]);
        WxL[col * 8 + 5] = f2bf(bg[hc]);
        WxL[col * 8 + 6] = 0; WxL[col * 8 + 7] = 0;
    }
    __syncthreads();
    if (tid < 2 * BS) Abuf[tid >> 2][(tid & 3) * STRIDE_A + 261] = 0x3F80;  // bias col = 1.0 (both bufs)
    if (tid < BS * DDYN) {                                                  // stage x(t=0) into buf 0
        int r = tid / DDYN, d = tid - r * DDYN;
        Abuf[0][r * STRIDE_A + 256 + d] = xc[r * DDYN + d];
    }

    // ---- persistent B fragments: 6 tiles (32 units x 3 gates) x 8 K-chunks = 192 VGPRs ----
    short8 Bf[NTILE][8];
    #pragma unroll
    for (int j = 0; j < NTILE; j++) {
        int g = j >> 1;
        int urow = wv * UPW + (j & 1) * 16 + n;
        const float* Wg = g == 0 ? W_f : (g == 1 ? W_g : W_o);
        const float* wrow = Wg + urow * (DDYN + HID) + DDYN;   // skip x-part
        #pragma unroll
        for (int c = 0; c < 8; c++) {
            int k0 = c * 32 + q * 8;
            short8 fr;
            #pragma unroll
            for (int e = 0; e < 8; e++) fr[e] = (short)f2bf(wrow[k0 + e]);
            Bf[j][c] = fr;
        }
    }

    // ---- i_gate for this thread's (unit u, rows r0, r0+1); head weight ----
    float ig0, ig1, c0 = 0.f, c1 = 0.f, h0f = 0.f, h1f = 0.f;
    {
        float a0 = b_i[u], a1 = a0;
        for (int s = 0; s < NS; s++) {
            float w = W_i[u * NS + s];
            a0 += xst[r0 * NS + s] * w;
            a1 += xst[(r0 + 1) * NS + s] * w;
        }
        ig0 = fsig(a0); ig1 = fsig(a1);
    }
    const float whead = W_head[u];
    __syncthreads();

    const int aoff = n * STRIDE_A;
    const int pb   = (wv * 96 + ul) * 4 + r0;   // pre float index for (gate 0, unit u, row r0)

    // ---- time loop: ONE barrier per step (Abuf double-buffered, pre is intra-wave) ----
    for (int t = 0; t < TS; t++) {
        const unsigned short* __restrict__ pA = Abuf[t & 1];
        unsigned short*       __restrict__ pB = Abuf[(t + 1) & 1];

        // Phase A: preacts for this wave's 96 columns = [h | x | 1] @ [Wh | Wx | b]^T
        f32x4 acc[NTILE];
        #pragma unroll
        for (int j = 0; j < NTILE; j++) acc[j] = (f32x4){0.f, 0.f, 0.f, 0.f};
        #pragma unroll
        for (int c = 0; c < 8; c++) {
            short8 a = *(const short8*)&pA[aoff + c * 32 + q * 8];
            #pragma unroll
            for (int j = 0; j < NTILE; j++)
                acc[j] = __builtin_amdgcn_mfma_f32_16x16x32_bf16(a, Bf[j][c], acc[j], 0, 0, 0);
        }
        {   // K-chunk 8: x-part + bias (A cols 262..287 are zero)
            short8 a8 = *(const short8*)&pA[aoff + 256 + q * 8];
            #pragma unroll
            for (int j = 0; j < NTILE; j++) {
                short8 b8 = {};
                if (q == 0) {
                    int col = (j >> 1) * 256 + wv * UPW + (j & 1) * 16 + n;
                    b8 = *(const short8*)&WxL[col * 8];
                }
                acc[j] = __builtin_amdgcn_mfma_f32_16x16x32_bf16(a8, b8, acc[j], 0, 0, 0);
            }
        }
        if (q == 0) {   // lanes 0..15: rows 0..3 of col -> pre[(wv*96 + g*32 + ulocal)][r]
            #pragma unroll
            for (int j = 0; j < NTILE; j++)
                *(f32x4*)&pre[(wv * 96 + (j >> 1) * 32 + (j & 1) * 16 + n) * 4] = acc[j];
        }
        // intra-wave exchange: wave's own writes -> wave's own reads
        __asm__ volatile("s_waitcnt lgkmcnt(0)" ::: "memory");

        // Phase B: LSTM cell for (unit u, rows r0, r0+1)
        f32x2 pf = *(const f32x2*)&pre[pb];
        f32x2 pg = *(const f32x2*)&pre[pb + 128];
        f32x2 po = *(const f32x2*)&pre[pb + 256];
        {
            float f  = fsig(pf[0]);
            float g_ = ftanh(pg[0]);
            float o  = fsig(po[0]);
            c0 = f * c0 + ig0 * g_;
            float h = o * ftanh(c0);
            pB[r0 * STRIDE_A + u] = f2bf(h);
            if (t == TS - 1) h0f = h;
        }
        {
            float f  = fsig(pf[1]);
            float g_ = ftanh(pg[1]);
            float o  = fsig(po[1]);
            c1 = f * c1 + ig1 * g_;
            float h = o * ftanh(c1);
            pB[(r0 + 1) * STRIDE_A + u] = f2bf(h);
            if (t == TS - 1) h1f = h;
        }
        if (t + 1 < TS && tid < BS * DDYN) {   // stage x(t+1) into next buffer
            int r = tid / DDYN, d = tid - r * DDYN;
            pB[r * STRIDE_A + 256 + d] = xc[(t + 1) * 20 + tid];
        }
        __syncthreads();
    }

    // ---- head: out[b] = h . W_head + b_head ----
    pre[u * 4 + r0]     = h0f * whead;
    pre[u * 4 + r0 + 1] = h1f * whead;
    __syncthreads();
    if (tid < 64) {
        f32x4 s = *(const f32x4*)&pre[tid * 4];
        #pragma unroll
        for (int k = 1; k < 4; k++) {
            f32x4 v = *(const f32x4*)&pre[(tid + k * 64) * 4];
            #pragma unroll
            for (int r = 0; r < BS; r++) s[r] += v[r];
        }
        #pragma unroll
        for (int off = 32; off > 0; off >>= 1)
            #pragma unroll
            for (int r = 0; r < BS; r++) s[r] += __shfl_down(s[r], off, 64);
        if (tid == 0) {
            float bh = b_head[0];
            #pragma unroll
            for (int r = 0; r < BS; r++) out[b0 + r] = s[r] + bh;
        }
    }
}

extern "C" void kernel_launch(void* const* d_in, const int* in_sizes, int n_in,
                              void* d_out, int out_size, void* d_ws, size_t ws_size,
                              hipStream_t stream) {
    ealstm_kernel<<<256, 512, 0, stream>>>(
        (const float*)d_in[0],  (const float*)d_in[1],  (const float*)d_in[2],
        (const float*)d_in[3],  (const float*)d_in[4],  (const float*)d_in[5],
        (const float*)d_in[6],  (const float*)d_in[7],  (const float*)d_in[8],
        (const float*)d_in[9],  (const float*)d_in[10], (const float*)d_in[11],
        (float*)d_out);
}

// Round 3
// 696.698 us; speedup vs baseline: 1.3534x; 1.0161x over previous
//
#include <hip/hip_runtime.h>

#define HID      256
#define DDYN     5
#define NS       27
#define TS       365
#define BS       4          // batch rows per block
#define NW       8          // waves per block
#define UPW      32         // hidden units owned per wave
#define NTILE    6          // 16-col MFMA tiles per wave (32 units x 3 gates / 16)
#define STRIDE_A 296        // A-buffer row stride in bf16 elems (256 h + 32 xpad + 8 pad)
#define G3       768        // 3 gates * 256

typedef short short8 __attribute__((ext_vector_type(8)));
typedef float f32x4  __attribute__((ext_vector_type(4)));
typedef float f32x2  __attribute__((ext_vector_type(2)));

__device__ __forceinline__ unsigned short f2bf(float f) {
    union { float f; unsigned u; } v; v.f = f;
    unsigned r = v.u + 0x7FFFu + ((v.u >> 16) & 1u);   // RNE
    return (unsigned short)(r >> 16);
}
__device__ __forceinline__ float fsig(float x) {
    float e = __builtin_amdgcn_exp2f(-1.4426950408889634f * x);
    return __builtin_amdgcn_rcpf(1.0f + e);
}
__device__ __forceinline__ float ftanh(float x) {
    float e = __builtin_amdgcn_exp2f(2.8853900817779268f * x);
    return 1.0f - 2.0f * __builtin_amdgcn_rcpf(1.0f + e);
}

// amdgpu_waves_per_eu(2,2): pin allocator to EXACTLY 2 waves/EU -> 256-VGPR cap.
// R2 evidence: plain __launch_bounds__(512,2) let the allocator target 4 waves/EU
// (128 VGPRs) and spill ~100 regs (WRITE_SIZE 88 MB of spill stores) even though
// the grid (1 block/CU) can never realize that occupancy.
__global__ __launch_bounds__(512)
__attribute__((amdgpu_waves_per_eu(2, 2)))
void ealstm_kernel(const float* __restrict__ x_dyn,  const float* __restrict__ x_stat,
                   const float* __restrict__ W_i,    const float* __restrict__ b_i,
                   const float* __restrict__ W_f,    const float* __restrict__ b_f,
                   const float* __restrict__ W_g,    const float* __restrict__ b_g,
                   const float* __restrict__ W_o,    const float* __restrict__ b_o,
                   const float* __restrict__ W_head, const float* __restrict__ b_head,
                   float* __restrict__ out)
{
    // LDS: 18944 + 12288 + 12288 + 14600 + 432 = ~58.6 KB (1 block/CU)
    __shared__ __align__(16) unsigned short Abuf[2][16 * STRIDE_A]; // double-buffered A tile
    __shared__ __align__(16) float          pre[G3 * 4];            // preacts [col][4 rows]
    __shared__ __align__(16) unsigned short WxL[G3 * 8];            // B rows 256..263: Wx[0..4],bias,0,0
    __shared__ __align__(16) unsigned short xc[TS * 20];            // x cache [t][b][d] bf16
    __shared__ __align__(16) float          xst[BS * NS];

    const int tid  = threadIdx.x;
    const int bid  = blockIdx.x;
    const int b0   = bid * BS;
    const int lane = tid & 63;
    const int wv   = tid >> 6;        // wave 0..7
    const int q    = lane >> 4;       // quad 0..3 (MFMA K-group)
    const int n    = lane & 15;       // MFMA col-in-tile / batch row for A
    const int ul   = lane & 31;       // unit-local 0..31 (phase B)
    const int r0   = (lane >> 5) * 2; // rows {0,1} or {2,3} (phase B)
    const int u    = wv * UPW + ul;   // owned hidden unit

    // ---- init LDS ----
    for (int i = tid; i < 2 * 16 * STRIDE_A / 2; i += 512)
        ((unsigned int*)Abuf)[i] = 0u;                 // zero both A buffers
    for (int i = tid; i < BS * NS; i += 512)
        xst[i] = x_stat[(b0 + i / NS) * NS + (i % NS)];
    for (int i = tid; i < TS * BS * DDYN; i += 512) {
        int b  = i / (TS * DDYN);
        int rr = i - b * (TS * DDYN);
        int t  = rr / DDYN;
        int d  = rr - t * DDYN;
        xc[t * 20 + b * DDYN + d] =
            f2bf(x_dyn[(size_t)(b0 + b) * (TS * DDYN) + t * DDYN + d]);
    }
    for (int col = tid; col < G3; col += 512) {
        int gate = col >> 8, hc = col & 255;
        const float* Wg = gate == 0 ? W_f : (gate == 1 ? W_g : W_o);
        const float* bg = gate == 0 ? b_f : (gate == 1 ? b_g : b_o);
        #pragma unroll
        for (int d = 0; d < DDYN; d++) WxL[col * 8 + d] = f2bf(Wg[hc * (DDYN + HID) + d]);
        WxL[col * 8 + 5] = f2bf(bg[hc]);
        WxL[col * 8 + 6] = 0; WxL[col * 8 + 7] = 0;
    }
    __syncthreads();
    if (tid < 2 * BS) Abuf[tid >> 2][(tid & 3) * STRIDE_A + 261] = 0x3F80;  // bias col = 1.0 (both bufs)
    if (tid < BS * DDYN) {                                                  // stage x(t=0) into buf 0
        int r = tid / DDYN, d = tid - r * DDYN;
        Abuf[0][r * STRIDE_A + 256 + d] = xc[r * DDYN + d];
    }

    // ---- persistent B fragments: 6 tiles (32 units x 3 gates) x 8 K-chunks = 192 VGPRs ----
    short8 Bf[NTILE][8];
    #pragma unroll
    for (int j = 0; j < NTILE; j++) {
        int g = j >> 1;
        int urow = wv * UPW + (j & 1) * 16 + n;
        const float* Wg = g == 0 ? W_f : (g == 1 ? W_g : W_o);
        const float* wrow = Wg + urow * (DDYN + HID) + DDYN;   // skip x-part
        #pragma unroll
        for (int c = 0; c < 8; c++) {
            int k0 = c * 32 + q * 8;
            short8 fr;
            #pragma unroll
            for (int e = 0; e < 8; e++) fr[e] = (short)f2bf(wrow[k0 + e]);
            Bf[j][c] = fr;
        }
    }

    // ---- i_gate for this thread's (unit u, rows r0, r0+1); head weight ----
    float ig0, ig1, c0 = 0.f, c1 = 0.f, h0f = 0.f, h1f = 0.f;
    {
        float a0 = b_i[u], a1 = a0;
        for (int s = 0; s < NS; s++) {
            float w = W_i[u * NS + s];
            a0 += xst[r0 * NS + s] * w;
            a1 += xst[(r0 + 1) * NS + s] * w;
        }
        ig0 = fsig(a0); ig1 = fsig(a1);
    }
    const float whead = W_head[u];
    __syncthreads();

    const int aoff = n * STRIDE_A;
    const int pb   = (wv * 96 + ul) * 4 + r0;   // pre float index for (gate 0, unit u, row r0)

    // ---- time loop: ONE barrier per step (Abuf double-buffered, pre is intra-wave) ----
    for (int t = 0; t < TS; t++) {
        const unsigned short* __restrict__ pA = Abuf[t & 1];
        unsigned short*       __restrict__ pB = Abuf[(t + 1) & 1];

        // Phase A: preacts for this wave's 96 columns = [h | x | 1] @ [Wh | Wx | b]^T
        f32x4 acc[NTILE];
        #pragma unroll
        for (int j = 0; j < NTILE; j++) acc[j] = (f32x4){0.f, 0.f, 0.f, 0.f};
        #pragma unroll
        for (int c = 0; c < 8; c++) {
            short8 a = *(const short8*)&pA[aoff + c * 32 + q * 8];
            #pragma unroll
            for (int j = 0; j < NTILE; j++)
                acc[j] = __builtin_amdgcn_mfma_f32_16x16x32_bf16(a, Bf[j][c], acc[j], 0, 0, 0);
        }
        {   // K-chunk 8: x-part + bias (A cols 262..287 are zero)
            short8 a8 = *(const short8*)&pA[aoff + 256 + q * 8];
            #pragma unroll
            for (int j = 0; j < NTILE; j++) {
                short8 b8 = {};
                if (q == 0) {
                    int col = (j >> 1) * 256 + wv * UPW + (j & 1) * 16 + n;
                    b8 = *(const short8*)&WxL[col * 8];
                }
                acc[j] = __builtin_amdgcn_mfma_f32_16x16x32_bf16(a8, b8, acc[j], 0, 0, 0);
            }
        }
        if (q == 0) {   // lanes 0..15: rows 0..3 of col -> pre[(wv*96 + g*32 + ulocal)][r]
            #pragma unroll
            for (int j = 0; j < NTILE; j++)
                *(f32x4*)&pre[(wv * 96 + (j >> 1) * 32 + (j & 1) * 16 + n) * 4] = acc[j];
        }
        // intra-wave exchange: wave's own writes -> wave's own reads
        __asm__ volatile("s_waitcnt lgkmcnt(0)" ::: "memory");

        // Phase B: LSTM cell for (unit u, rows r0, r0+1)
        f32x2 pf = *(const f32x2*)&pre[pb];
        f32x2 pg = *(const f32x2*)&pre[pb + 128];
        f32x2 po = *(const f32x2*)&pre[pb + 256];
        {
            float f  = fsig(pf[0]);
            float g_ = ftanh(pg[0]);
            float o  = fsig(po[0]);
            c0 = f * c0 + ig0 * g_;
            float h = o * ftanh(c0);
            pB[r0 * STRIDE_A + u] = f2bf(h);
            if (t == TS - 1) h0f = h;
        }
        {
            float f  = fsig(pf[1]);
            float g_ = ftanh(pg[1]);
            float o  = fsig(po[1]);
            c1 = f * c1 + ig1 * g_;
            float h = o * ftanh(c1);
            pB[(r0 + 1) * STRIDE_A + u] = f2bf(h);
            if (t == TS - 1) h1f = h;
        }
        if (t + 1 < TS && tid < BS * DDYN) {   // stage x(t+1) into next buffer
            int r = tid / DDYN, d = tid - r * DDYN;
            pB[r * STRIDE_A + 256 + d] = xc[(t + 1) * 20 + tid];
        }
        __syncthreads();
    }

    // ---- head: out[b] = h . W_head + b_head ----
    pre[u * 4 + r0]     = h0f * whead;
    pre[u * 4 + r0 + 1] = h1f * whead;
    __syncthreads();
    if (tid < 64) {
        f32x4 s = *(const f32x4*)&pre[tid * 4];
        #pragma unroll
        for (int k = 1; k < 4; k++) {
            f32x4 v = *(const f32x4*)&pre[(tid + k * 64) * 4];
            #pragma unroll
            for (int r = 0; r < BS; r++) s[r] += v[r];
        }
        #pragma unroll
        for (int off = 32; off > 0; off >>= 1)
            #pragma unroll
            for (int r = 0; r < BS; r++) s[r] += __shfl_down(s[r], off, 64);
        if (tid == 0) {
            float bh = b_head[0];
            #pragma unroll
            for (int r = 0; r < BS; r++) out[b0 + r] = s[r] + bh;
        }
    }
}

extern "C" void kernel_launch(void* const* d_in, const int* in_sizes, int n_in,
                              void* d_out, int out_size, void* d_ws, size_t ws_size,
                              hipStream_t stream) {
    ealstm_kernel<<<256, 512, 0, stream>>>(
        (const float*)d_in[0],  (const float*)d_in[1],  (const float*)d_in[2],
        (const float*)d_in[3],  (const float*)d_in[4],  (const float*)d_in[5],
        (const float*)d_in[6],  (const float*)d_in[7],  (const float*)d_in[8],
        (const float*)d_in[9],  (const float*)d_in[10], (const float*)d_in[11],
        (float*)d_out);
}